// Round 1
// baseline (233.447 us; speedup 1.0000x reference)
//
#include <hip/hip_runtime.h>
#include <hip/hip_bf16.h>
#include <stdint.h>

#define DI __device__ __forceinline__

typedef __attribute__((ext_vector_type(8))) short short8;
typedef __attribute__((ext_vector_type(4))) float f32x4;

static constexpr int TT = 4096;   // seq len
static constexpr int CC = 1024;   // n_embed
static constexpr int HH = 64;     // head size
static constexpr int NB = 4;      // batch

DI short f2b(float x) {
  __hip_bfloat16 h = __float2bfloat16(x);
  return __builtin_bit_cast(short, h);
}

DI f32x4 MFMA(short8 a, short8 b, f32x4 c) {
  return __builtin_amdgcn_mfma_f32_16x16x32_bf16(a, b, c, 0, 0, 0);
}

DI void gload_lds16(const void* g, void* l) {
  __builtin_amdgcn_global_load_lds(
      (__attribute__((address_space(1))) void*)(void*)(uintptr_t)g,
      (__attribute__((address_space(3))) void*)(void*)(uintptr_t)l, 16, 0, 0);
}

// ---------------------------------------------------------------------------
// Kernel 0: transpose weights W[k][n] f32 -> Wt[mat][n][k] bf16  (3*64*1024)
// ---------------------------------------------------------------------------
__global__ __launch_bounds__(256) void prep_wt(const float* __restrict__ Wq,
                                               const float* __restrict__ Wk,
                                               const float* __restrict__ Wv,
                                               short* __restrict__ Wt) {
  int o = blockIdx.x * 256 + threadIdx.x;       // < 196608
  int mat = o >> 16;
  int rem = o & 65535;
  int n = rem >> 10;
  int k = rem & 1023;
  const float* W = (mat == 0) ? Wq : ((mat == 1) ? Wk : Wv);
  Wt[o] = f2b(W[k * HH + n]);
}

// ---------------------------------------------------------------------------
// Kernel 1: fused QKV projection.  x[16384][1024] f32 @ Wt -> qb/kb/vb bf16.
// q gets scale (1/8)*log2(e) folded in (exp2-domain softmax downstream).
// Block: 64 rows x 192 cols, 4 waves; wave w: nf in {3w..3w+2}, all 4 mf.
// ---------------------------------------------------------------------------
__global__ __launch_bounds__(256) void qkv_gemm(const float* __restrict__ x,
                                                const short* __restrict__ Wt,
                                                const float* __restrict__ bq,
                                                const float* __restrict__ bk,
                                                const float* __restrict__ bv,
                                                short* __restrict__ qb,
                                                short* __restrict__ kb,
                                                short* __restrict__ vb) {
  __shared__ short lds_a[64 * 64];       // [row][k] 128B rows, xor-swizzled
  __shared__ short lds_b[3 * 64 * 64];   // [mat][n][k] 128B rows, xor-swizzled

  const int tid = threadIdx.x;
  const int w = tid >> 6;
  const int lane = tid & 63;
  const int c = lane & 15, g = lane >> 4;
  const int m0 = blockIdx.x * 64;

  f32x4 acc[4][3] = {};   // [mf][i]

  for (int kt = 0; kt < 16; ++kt) {
    const int k0 = kt * 64;
    __syncthreads();
    // ---- stage A (f32 -> bf16 via registers), xor-swizzled LDS write
    {
      int r = tid >> 2, q4 = tid & 3;
      const float* src = x + (size_t)(m0 + r) * CC + k0 + q4 * 16;
      float4 v0 = ((const float4*)src)[0];
      float4 v1 = ((const float4*)src)[1];
      float4 v2 = ((const float4*)src)[2];
      float4 v3 = ((const float4*)src)[3];
      short8 p0, p1;
      p0[0] = f2b(v0.x); p0[1] = f2b(v0.y); p0[2] = f2b(v0.z); p0[3] = f2b(v0.w);
      p0[4] = f2b(v1.x); p0[5] = f2b(v1.y); p0[6] = f2b(v1.z); p0[7] = f2b(v1.w);
      p1[0] = f2b(v2.x); p1[1] = f2b(v2.y); p1[2] = f2b(v2.z); p1[3] = f2b(v2.w);
      p1[4] = f2b(v3.x); p1[5] = f2b(v3.y); p1[6] = f2b(v3.z); p1[7] = f2b(v3.w);
      int sw = (r & 7) << 4;
      char* base = (char*)lds_a + r * 128;
      *(short8*)(base + ((q4 * 32) ^ sw)) = p0;
      *(short8*)(base + ((q4 * 32 + 16) ^ sw)) = p1;
    }
    // ---- stage B: 3 x 64n x 64k bf16 tiles via global_load_lds(16B),
    //      swizzle applied on SOURCE address, LDS linear (rule #21)
#pragma unroll
    for (int it = 0; it < 6; ++it) {
      int chunk = it * 4 + w;           // 24 chunks of 64 slots
      int slot = chunk * 64 + lane;     // 0..1535
      int mat = slot >> 9;
      int s = slot & 511;
      int r = s >> 3;
      int c16 = (s & 7) ^ (r & 7);
      gload_lds16(Wt + mat * 65536 + r * CC + k0 + c16 * 8,
                  (short*)lds_b + chunk * 512);
    }
    __syncthreads();
    // ---- compute
    short8 afr[4][2];
#pragma unroll
    for (int mf = 0; mf < 4; ++mf)
#pragma unroll
      for (int ks = 0; ks < 2; ++ks) {
        int row = 16 * mf + c;
        afr[mf][ks] = *(const short8*)((const char*)lds_a + row * 128 +
                                       ((ks * 64 + g * 16) ^ ((row & 7) << 4)));
      }
#pragma unroll
    for (int i = 0; i < 3; ++i) {
      int nf = 3 * w + i;
      int mat = nf >> 2;
      int n = (nf & 3) * 16 + c;
#pragma unroll
      for (int ks = 0; ks < 2; ++ks) {
        short8 bfr = *(const short8*)((const char*)lds_b + mat * 8192 + n * 128 +
                                      ((ks * 64 + g * 16) ^ ((n & 7) << 4)));
#pragma unroll
        for (int mf = 0; mf < 4; ++mf)
          acc[mf][i] = MFMA(afr[mf][ks], bfr, acc[mf][i]);
      }
    }
  }
  // ---- epilogue: +bias, scale (q only), bf16 store
  const float QSCALE = 0.125f * 1.44269504088896340736f;  // 1/sqrt(64) * log2(e)
#pragma unroll
  for (int i = 0; i < 3; ++i) {
    int nf = 3 * w + i;
    int mat = nf >> 2;
    int col = (nf & 3) * 16 + c;
    const float* bp = (mat == 0) ? bq : ((mat == 1) ? bk : bv);
    short* op = (mat == 0) ? qb : ((mat == 1) ? kb : vb);
    float bias = bp[col];
    float scale = (mat == 0) ? QSCALE : 1.0f;
#pragma unroll
    for (int mf = 0; mf < 4; ++mf)
#pragma unroll
      for (int r = 0; r < 4; ++r) {
        int m = m0 + 16 * mf + 4 * g + r;
        op[(size_t)m * HH + col] = f2b((acc[mf][i][r] + bias) * scale);
      }
  }
}

// ---------------------------------------------------------------------------
// Kernel 2: V transpose  vb[b*T+t][h] -> vT[b][h][t]   (64x64 LDS tiles)
// ---------------------------------------------------------------------------
__global__ __launch_bounds__(256) void v_trans(const short* __restrict__ vb,
                                               short* __restrict__ vT) {
  __shared__ short lds[64 * 72];
  int t0 = blockIdx.x * 64;
  int b = blockIdx.y;
  int tid = threadIdx.x;
#pragma unroll
  for (int it = 0; it < 2; ++it) {
    int slot = it * 256 + tid;
    int r = slot >> 3, c8 = slot & 7;
    short8 v = *(const short8*)(vb + (size_t)(b * TT + t0 + r) * HH + c8 * 8);
    *(short8*)(lds + r * 72 + c8 * 8) = v;   // 144B rows: 16B aligned
  }
  __syncthreads();
  int h = tid >> 2, tc = tid & 3;
  short tmp[16];
#pragma unroll
  for (int i = 0; i < 16; ++i) tmp[i] = lds[(tc * 16 + i) * 72 + h];
  short8 o0, o1;
#pragma unroll
  for (int i = 0; i < 8; ++i) { o0[i] = tmp[i]; o1[i] = tmp[8 + i]; }
  short8* outp = (short8*)(vT + (size_t)(b * HH + h) * TT + t0 + tc * 16);
  outp[0] = o0;
  outp[1] = o1;
}

// ---------------------------------------------------------------------------
// Kernel 3: causal flash attention.
// Block = (qt, b): 64 q-rows, 4 waves x 16 rows. KV tiles of 64.
// Scores already in exp2 domain (scale folded into q).
// ---------------------------------------------------------------------------
__global__ __launch_bounds__(256) void attn(const short* __restrict__ qb,
                                            const short* __restrict__ kb,
                                            const short* __restrict__ vT,
                                            float* __restrict__ out) {
  __shared__ short lds_k[64 * 64];          // [kt][h] 128B rows, xor-swizzled
  __shared__ short lds_v[64 * 64];          // [h][kt] 128B rows, xor-swizzled
  __shared__ short lds_p[4 * 16 * 72];      // per-wave P, stride-72 pad

  const int qt = blockIdx.x;
  const int b = blockIdx.y;
  const int q0 = qt * 64;
  const int tid = threadIdx.x;
  const int w = tid >> 6, lane = tid & 63;
  const int c = lane & 15, g = lane >> 4;

  // Q fragments (A-operand), held in registers for the whole block
  short8 qfr[2];
  {
    const short* qrow = qb + (size_t)(b * TT + q0 + 16 * w + c) * HH;
    qfr[0] = *(const short8*)(qrow + g * 8);
    qfr[1] = *(const short8*)(qrow + 32 + g * 8);
  }

  f32x4 acc_o[4] = {};
  float mreg[4], lreg[4];
#pragma unroll
  for (int r = 0; r < 4; ++r) { mreg[r] = -INFINITY; lreg[r] = 0.f; }

  const int nt = qt + 1;
  for (int tt = 0; tt < nt; ++tt) {
    const int kv0 = tt * 64;
    __syncthreads();
    // ---- stage K [kt][h] and V^T [h][kt] via global_load_lds, source-swizzled
#pragma unroll
    for (int it = 0; it < 2; ++it) {
      int chunk = it * 4 + w;
      int slot = chunk * 64 + lane;
      int r = slot >> 3;
      int c16 = (slot & 7) ^ (r & 7);
      gload_lds16(kb + (size_t)(b * TT + kv0 + r) * HH + c16 * 8,
                  (short*)lds_k + chunk * 512);
      gload_lds16(vT + (size_t)(b * HH + r) * TT + kv0 + c16 * 8,
                  (short*)lds_v + chunk * 512);
    }
    __syncthreads();

    // ---- S^ = Q K^T (exp2 domain).  sc[nf] elem: q=4g+r (wave-local), kt=16nf+c
    f32x4 sc[4] = {};
    const int sw = (c & 7) << 4;
#pragma unroll
    for (int nf = 0; nf < 4; ++nf) {
      const char* krow = (const char*)lds_k + (16 * nf + c) * 128;
      short8 k0 = *(const short8*)(krow + ((g * 16) ^ sw));
      short8 k1 = *(const short8*)(krow + ((64 + g * 16) ^ sw));
      sc[nf] = MFMA(qfr[0], k0, sc[nf]);
      sc[nf] = MFMA(qfr[1], k1, sc[nf]);
    }

    // ---- causal mask (diagonal tile only)
    if (tt == nt - 1) {
#pragma unroll
      for (int nf = 0; nf < 4; ++nf)
#pragma unroll
        for (int r = 0; r < 4; ++r) {
          int ktg = kv0 + 16 * nf + c;
          int qg = q0 + 16 * w + 4 * g + r;
          if (ktg > qg) sc[nf][r] = -INFINITY;
        }
    }

    // ---- online softmax (exp2 domain), per q-row reduce over 16-lane group
    float mn[4], al[4], rs[4];
#pragma unroll
    for (int r = 0; r < 4; ++r) {
      float v = fmaxf(fmaxf(sc[0][r], sc[1][r]), fmaxf(sc[2][r], sc[3][r]));
      v = fmaxf(v, __shfl_xor(v, 1));
      v = fmaxf(v, __shfl_xor(v, 2));
      v = fmaxf(v, __shfl_xor(v, 4));
      v = fmaxf(v, __shfl_xor(v, 8));
      mn[r] = fmaxf(mreg[r], v);
      al[r] = exp2f(mreg[r] - mn[r]);
      rs[r] = 0.f;
    }
    // P = exp2(s - m), bf16, to wave-private LDS (D-layout -> A-layout transpose)
    short* pw = lds_p + w * 1152;
#pragma unroll
    for (int nf = 0; nf < 4; ++nf)
#pragma unroll
      for (int r = 0; r < 4; ++r) {
        float p = exp2f(sc[nf][r] - mn[r]);
        rs[r] += p;
        pw[(4 * g + r) * 72 + 16 * nf + c] = f2b(p);
      }
#pragma unroll
    for (int r = 0; r < 4; ++r) {
      float v = rs[r];
      v += __shfl_xor(v, 1);
      v += __shfl_xor(v, 2);
      v += __shfl_xor(v, 4);
      v += __shfl_xor(v, 8);
      lreg[r] = al[r] * lreg[r] + v;
      mreg[r] = mn[r];
    }
#pragma unroll
    for (int hf = 0; hf < 4; ++hf)
#pragma unroll
      for (int r = 0; r < 4; ++r) acc_o[hf][r] *= al[r];

    // ---- O += P V   (A from lds_p, B from V^T rows)
    const char* pb = (const char*)lds_p + w * 2304;
#pragma unroll
    for (int ks = 0; ks < 2; ++ks) {
      short8 pa = *(const short8*)(pb + c * 144 + ks * 64 + g * 16);
#pragma unroll
      for (int hf = 0; hf < 4; ++hf) {
        const char* vrow = (const char*)lds_v + (16 * hf + c) * 128;
        short8 vf = *(const short8*)(vrow + ((ks * 64 + g * 16) ^ sw));
        acc_o[hf] = MFMA(pa, vf, acc_o[hf]);
      }
    }
  }

  // ---- epilogue: normalize and store f32
#pragma unroll
  for (int r = 0; r < 4; ++r) {
    float inv = 1.0f / lreg[r];
    int qg = q0 + 16 * w + 4 * g + r;
    float* orow = out + (size_t)(b * TT + qg) * HH;
#pragma unroll
    for (int hf = 0; hf < 4; ++hf)
      orow[16 * hf + c] = acc_o[hf][r] * inv;
  }
}

// ---------------------------------------------------------------------------
extern "C" void kernel_launch(void* const* d_in, const int* in_sizes, int n_in,
                              void* d_out, int out_size, void* d_ws, size_t ws_size,
                              hipStream_t stream) {
  const float* x  = (const float*)d_in[0];
  const float* Wq = (const float*)d_in[1];
  const float* bq = (const float*)d_in[2];
  const float* Wk = (const float*)d_in[3];
  const float* bk = (const float*)d_in[4];
  const float* Wv = (const float*)d_in[5];
  const float* bv = (const float*)d_in[6];
  float* out = (float*)d_out;

  char* ws = (char*)d_ws;
  short* Wt = (short*)ws;                           // 3*64*1024 bf16 = 384 KB
  short* qb = (short*)(ws + 393216);                // 16384*64 bf16 = 2 MB
  short* kb = qb + 16384 * 64;
  short* vb = kb + 16384 * 64;
  short* vT = vb + 16384 * 64;                      // total ~8.4 MB

  prep_wt<<<dim3(768), dim3(256), 0, stream>>>(Wq, Wk, Wv, Wt);
  qkv_gemm<<<dim3(256), dim3(256), 0, stream>>>(x, Wt, bq, bk, bv, qb, kb, vb);
  v_trans<<<dim3(64, 4), dim3(256), 0, stream>>>(vb, vT);
  attn<<<dim3(64, 4), dim3(256), 0, stream>>>(qb, kb, vT, out);
}

// Round 2
// 192.000 us; speedup vs baseline: 1.2159x; 1.2159x over previous
//
#include <hip/hip_runtime.h>
#include <hip/hip_bf16.h>
#include <stdint.h>

#define DI __device__ __forceinline__

typedef __attribute__((ext_vector_type(8))) short short8;
typedef __attribute__((ext_vector_type(4))) short short4v;
typedef __attribute__((ext_vector_type(4))) float f32x4;

static constexpr int TT = 4096;   // seq len
static constexpr int CC = 1024;   // n_embed
static constexpr int HH = 64;     // head size

DI short f2b(float x) {
  __hip_bfloat16 h = __float2bfloat16(x);
  return __builtin_bit_cast(short, h);
}

DI f32x4 MFMA(short8 a, short8 b, f32x4 c) {
  return __builtin_amdgcn_mfma_f32_16x16x32_bf16(a, b, c, 0, 0, 0);
}

// ---------------------------------------------------------------------------
// Kernel 0: transpose weights W[k][n] f32 -> Wt[mat][n][k] bf16  (3*64*1024)
// ---------------------------------------------------------------------------
__global__ __launch_bounds__(256) void prep_wt(const float* __restrict__ Wq,
                                               const float* __restrict__ Wk,
                                               const float* __restrict__ Wv,
                                               short* __restrict__ Wt) {
  int o = blockIdx.x * 256 + threadIdx.x;       // < 196608
  int mat = o >> 16;
  int rem = o & 65535;
  int n = rem >> 10;
  int k = rem & 1023;
  const float* W = (mat == 0) ? Wq : ((mat == 1) ? Wk : Wv);
  Wt[o] = f2b(W[k * HH + n]);
}

// ---------------------------------------------------------------------------
// Kernel 1: fused QKV projection. 512 blocks of 32 rows (2 blocks/CU).
// A tile staged in LDS (x read once); B fragments direct from L2-resident Wt.
// q gets (1/8)*log2(e) folded in. V written directly transposed to vT[b][h][t].
// ---------------------------------------------------------------------------
__global__ __launch_bounds__(256, 2) void qkv_gemm(const float* __restrict__ x,
                                                   const short* __restrict__ Wt,
                                                   const float* __restrict__ bq,
                                                   const float* __restrict__ bk,
                                                   const float* __restrict__ bv,
                                                   short* __restrict__ qb,
                                                   short* __restrict__ kb,
                                                   short* __restrict__ vT) {
  __shared__ short lds_a[32 * 64];       // [row][k] 128B rows, xor-swizzled

  const int tid = threadIdx.x;
  const int w = tid >> 6;
  const int lane = tid & 63;
  const int c = lane & 15, g = lane >> 4;
  const int m0 = blockIdx.x * 32;

  f32x4 acc[2][3] = {};   // [mf][i]

  for (int kt = 0; kt < 16; ++kt) {
    const int k0 = kt * 64;
    __syncthreads();
    // ---- stage A (f32 -> bf16), xor-swizzled LDS write. 8 elems/thread.
    {
      int r = tid >> 3, cs = tid & 7;
      const float* src = x + (size_t)(m0 + r) * CC + k0 + cs * 8;
      float4 v0 = ((const float4*)src)[0];
      float4 v1 = ((const float4*)src)[1];
      short8 p;
      p[0] = f2b(v0.x); p[1] = f2b(v0.y); p[2] = f2b(v0.z); p[3] = f2b(v0.w);
      p[4] = f2b(v1.x); p[5] = f2b(v1.y); p[6] = f2b(v1.z); p[7] = f2b(v1.w);
      *(short8*)((char*)lds_a + r * 128 + ((cs * 16) ^ ((r & 7) << 4))) = p;
    }
    __syncthreads();
    // ---- A fragments from LDS
    short8 afr[2][2];
#pragma unroll
    for (int mf = 0; mf < 2; ++mf)
#pragma unroll
      for (int ks = 0; ks < 2; ++ks) {
        int row = 16 * mf + c;
        afr[mf][ks] = *(const short8*)((const char*)lds_a + row * 128 +
                                       ((ks * 64 + g * 16) ^ ((row & 7) << 4)));
      }
    // ---- B fragments direct from global (Wt is L2-resident), MFMA
#pragma unroll
    for (int i = 0; i < 3; ++i) {
      int nf = 3 * w + i;
      int mat = nf >> 2;
      int nn = (nf & 3) * 16 + c;
#pragma unroll
      for (int ks = 0; ks < 2; ++ks) {
        short8 bfr = *(const short8*)(Wt + mat * 65536 + nn * CC + k0 +
                                      ks * 32 + g * 8);
#pragma unroll
        for (int mf = 0; mf < 2; ++mf)
          acc[mf][i] = MFMA(afr[mf][ks], bfr, acc[mf][i]);
      }
    }
  }
  // ---- epilogue
  const float QSCALE = 0.125f * 1.44269504088896340736f;  // 1/sqrt(64)*log2(e)
  const int bb = m0 >> 12;            // batch
  const int t0 = m0 & 4095;           // row within batch
#pragma unroll
  for (int i = 0; i < 3; ++i) {
    int nf = 3 * w + i;
    int mat = nf >> 2;
    int col = (nf & 3) * 16 + c;
    const float* bp = (mat == 0) ? bq : ((mat == 1) ? bk : bv);
    float bias = bp[col];
    if (mat < 2) {
      short* op = (mat == 0) ? qb : kb;
      float scale = (mat == 0) ? QSCALE : 1.0f;
#pragma unroll
      for (int mf = 0; mf < 2; ++mf)
#pragma unroll
        for (int r = 0; r < 4; ++r) {
          int m = m0 + 16 * mf + 4 * g + r;
          op[(size_t)m * HH + col] = f2b((acc[mf][i][r] + bias) * scale);
        }
    } else {
      // V direct-transposed: vT[b][col][t], 4 consecutive t -> short4 store
#pragma unroll
      for (int mf = 0; mf < 2; ++mf) {
        short4v pv;
#pragma unroll
        for (int r = 0; r < 4; ++r) pv[r] = f2b(acc[mf][i][r] + bias);
        *(short4v*)(vT + (size_t)(bb * HH + col) * TT + t0 + 16 * mf + 4 * g) = pv;
      }
    }
  }
}

// ---------------------------------------------------------------------------
// Kernel 2: causal flash attention, wave-independent (no barriers in loop).
// Grid (4 batches, 128 groups). Block = 32 q-rows: 4 waves = 2 jobs(16 rows)
// x 2 KV-halves. K/V^T fragments read DIRECT from global (L2-hot).
// End: partner waves merge (m,l,O) via LDS.
// Group order: first 64 blocks heavy-descending, last 64 light-ascending,
// so any (early,late) pair on a CU sums to ~const work.
// ---------------------------------------------------------------------------
__global__ __launch_bounds__(256, 2) void attn(const short* __restrict__ qb,
                                               const short* __restrict__ kb,
                                               const short* __restrict__ vT,
                                               float* __restrict__ out) {
  __shared__ short lds_p[4 * 16 * 72];      // per-wave P scratch (stride-72)
  __shared__ float lds_o[2 * 16 * 66];      // merge O, rows padded to 66
  __shared__ float lds_ml[2 * 2 * 16];      // merge m,l

  const int bb = blockIdx.x;                 // batch
  const int gy = blockIdx.y;                 // 0..127
  const int grp = (gy < 64) ? (127 - gy) : (gy - 64);
  const int tid = threadIdx.x;
  const int w = tid >> 6, lane = tid & 63;
  const int c = lane & 15, g = lane >> 4;

  const int jj = 2 * grp + (w & 1);          // 16-row job, 0..255
  const int s = w >> 1;                      // KV half
  const int q0 = jj * 16;                    // row within batch
  const int nT = (jj >> 2) + 1;              // causal KV tiles
  const int nTh = nT >> 1;
  const int tlo = s ? nTh : 0;
  const int thi = s ? nT : nTh;

  // Q fragments (held in registers)
  const short* qrow = qb + (size_t)(bb * TT + q0 + c) * HH;
  const short8 qfr0 = *(const short8*)(qrow + g * 8);
  const short8 qfr1 = *(const short8*)(qrow + 32 + g * 8);

  const short* kbase = kb + (size_t)bb * TT * HH;
  const short* vbase = vT + (size_t)bb * HH * TT;

  f32x4 acc[4] = {};
  float mreg[4], lreg[4];
#pragma unroll
  for (int r = 0; r < 4; ++r) { mreg[r] = -INFINITY; lreg[r] = 0.f; }

  short* pw = lds_p + w * 1152;
  const char* pb = (const char*)pw;

  for (int t = tlo; t < thi; ++t) {
    const int kv0 = t * 64;
    // ---- K and V fragments direct from global (issue early, pipeline)
    short8 kf[4][2], vf[4][2];
#pragma unroll
    for (int nf = 0; nf < 4; ++nf)
#pragma unroll
      for (int ks = 0; ks < 2; ++ks)
        kf[nf][ks] = *(const short8*)(kbase + (size_t)(kv0 + 16 * nf + c) * HH +
                                      ks * 32 + g * 8);
#pragma unroll
    for (int hf = 0; hf < 4; ++hf)
#pragma unroll
      for (int ks = 0; ks < 2; ++ks)
        vf[hf][ks] = *(const short8*)(vbase + (size_t)(16 * hf + c) * TT + kv0 +
                                      ks * 32 + g * 8);

    // ---- S^ = Q K^T (exp2 domain; scale folded into q)
    f32x4 sc[4] = {};
#pragma unroll
    for (int nf = 0; nf < 4; ++nf) {
      sc[nf] = MFMA(qfr0, kf[nf][0], sc[nf]);
      sc[nf] = MFMA(qfr1, kf[nf][1], sc[nf]);
    }

    // ---- causal mask (only the last tile of the causal range)
    if (t == nT - 1) {
#pragma unroll
      for (int nf = 0; nf < 4; ++nf)
#pragma unroll
        for (int r = 0; r < 4; ++r)
          if (kv0 + 16 * nf + c > q0 + 4 * g + r) sc[nf][r] = -INFINITY;
    }

    // ---- online softmax (row = 4g+r, reduce over 16 c-lanes)
    float mn[4], al[4], rs[4];
#pragma unroll
    for (int r = 0; r < 4; ++r) {
      float v = fmaxf(fmaxf(sc[0][r], sc[1][r]), fmaxf(sc[2][r], sc[3][r]));
      v = fmaxf(v, __shfl_xor(v, 1));
      v = fmaxf(v, __shfl_xor(v, 2));
      v = fmaxf(v, __shfl_xor(v, 4));
      v = fmaxf(v, __shfl_xor(v, 8));
      mn[r] = fmaxf(mreg[r], v);
      al[r] = exp2f(mreg[r] - mn[r]);
      rs[r] = 0.f;
    }
#pragma unroll
    for (int nf = 0; nf < 4; ++nf)
#pragma unroll
      for (int r = 0; r < 4; ++r) {
        float p = exp2f(sc[nf][r] - mn[r]);
        rs[r] += p;
        pw[(4 * g + r) * 72 + 16 * nf + c] = f2b(p);
      }
#pragma unroll
    for (int r = 0; r < 4; ++r) {
      float v = rs[r];
      v += __shfl_xor(v, 1);
      v += __shfl_xor(v, 2);
      v += __shfl_xor(v, 4);
      v += __shfl_xor(v, 8);
      lreg[r] = al[r] * lreg[r] + v;
      mreg[r] = mn[r];
    }
#pragma unroll
    for (int hf = 0; hf < 4; ++hf)
#pragma unroll
      for (int r = 0; r < 4; ++r) acc[hf][r] *= al[r];

    // ---- O += P V  (A from wave-private LDS, B = vf)
#pragma unroll
    for (int ks = 0; ks < 2; ++ks) {
      short8 pa = *(const short8*)(pb + c * 144 + ks * 64 + g * 16);
#pragma unroll
      for (int hf = 0; hf < 4; ++hf)
        acc[hf] = MFMA(pa, vf[hf][ks], acc[hf]);
    }
  }

  // ---- cross-wave merge: s=1 dumps to LDS, s=0 combines and stores
  __syncthreads();
  if (s == 1) {
    float* od = lds_o + (w & 1) * (16 * 66);
#pragma unroll
    for (int hf = 0; hf < 4; ++hf)
#pragma unroll
      for (int r = 0; r < 4; ++r)
        od[(4 * g + r) * 66 + 16 * hf + c] = acc[hf][r];
    if (c == 0) {
      float* ml = lds_ml + (w & 1) * 32;
#pragma unroll
      for (int r = 0; r < 4; ++r) {
        ml[4 * g + r] = mreg[r];
        ml[16 + 4 * g + r] = lreg[r];
      }
    }
  }
  __syncthreads();
  if (s == 0) {
    const float* od = lds_o + (w & 1) * (16 * 66);
    const float* ml = lds_ml + (w & 1) * 32;
#pragma unroll
    for (int r = 0; r < 4; ++r) {
      float m1 = ml[4 * g + r];
      float l1 = ml[16 + 4 * g + r];
      float m = fmaxf(mreg[r], m1);
      float a0 = exp2f(mreg[r] - m);
      float a1 = exp2f(m1 - m);
      float inv = 1.0f / (a0 * lreg[r] + a1 * l1);
      float* orow = out + (size_t)(bb * TT + q0 + 4 * g + r) * HH;
#pragma unroll
      for (int hf = 0; hf < 4; ++hf)
        orow[16 * hf + c] =
            (a0 * acc[hf][r] + a1 * od[(4 * g + r) * 66 + 16 * hf + c]) * inv;
    }
  }
}

// ---------------------------------------------------------------------------
extern "C" void kernel_launch(void* const* d_in, const int* in_sizes, int n_in,
                              void* d_out, int out_size, void* d_ws, size_t ws_size,
                              hipStream_t stream) {
  const float* x  = (const float*)d_in[0];
  const float* Wq = (const float*)d_in[1];
  const float* bq = (const float*)d_in[2];
  const float* Wk = (const float*)d_in[3];
  const float* bk = (const float*)d_in[4];
  const float* Wv = (const float*)d_in[5];
  const float* bv = (const float*)d_in[6];
  float* out = (float*)d_out;

  char* ws = (char*)d_ws;
  short* Wt = (short*)ws;                           // 3*64*1024 bf16 = 384 KB
  short* qb = (short*)(ws + 393216);                // 16384*64 bf16 = 2 MB
  short* kb = qb + 16384 * 64;
  short* vT = kb + 16384 * 64;                      // total ~6.4 MB

  prep_wt<<<dim3(768), dim3(256), 0, stream>>>(Wq, Wk, Wv, Wt);
  qkv_gemm<<<dim3(512), dim3(256), 0, stream>>>(x, Wt, bq, bk, bv, qb, kb, vT);
  attn<<<dim3(4, 128), dim3(256), 0, stream>>>(qb, kb, vT, out);
}